// Round 7
// baseline (543.769 us; speedup 1.0000x reference)
//
#include <hip/hip_runtime.h>

// MEASUREMENT PROBE R7 (intentional ~5x memory traffic; correct output).
// Goal: surface this kernel in rocprof top-5 with its own FETCH_SIZE so the
// achieved cold-stream BW of our access pattern is measured directly.
// Real et pass (exact R5 math, plain loads) + 4 cold 268MB sweeps of d_ws
// (same pattern, dummy accumulator kept live via runtime-false flag store).

constexpr int B = 64;
constexpr int I = 1024;
constexpr int O = 1024;
constexpr int ROWS_PER_WAVE = 4;
constexpr int BLOCKS = (B * O) / (ROWS_PER_WAVE * 4);   // 4096
constexpr size_t REGION_IV4 = (size_t)B * O * I / 4;     // 16,777,216 iv4 = 268.4 MB

typedef int   iv4 __attribute__((ext_vector_type(4)));
typedef float fv4 __attribute__((ext_vector_type(4)));

__global__ __launch_bounds__(256) void ffcl_probe(
    const float* __restrict__ x,       // [B, I]
    const int*   __restrict__ et,      // [B, O, I]
    const int*   __restrict__ op,      // [O]
    float*       __restrict__ out,     // [B, O]
    const int*   __restrict__ ws,      // >= nws * 268.4 MB, cold-poisoned
    int nws, long flag)                // flag==0 at runtime (opaque)
{
    const int t      = threadIdx.x;
    const int wid    = t >> 6;
    const int lane   = t & 63;
    const int wave   = blockIdx.x * 4 + wid;
    const int r_base = wave * ROWS_PER_WAVE;
    const int b      = r_base >> 10;
    const int o_base = r_base & (O - 1);

    // x strip and 1-x (shared by all passes)
    fv4 xv[4], qv[4];
    #pragma unroll
    for (int j = 0; j < 4; ++j) {
        xv[j] = *reinterpret_cast<const fv4*>(x + (size_t)b * I + j * 256 + lane * 4);
        qv[j].x = 1.0f - xv[j].x;  qv[j].y = 1.0f - xv[j].y;
        qv[j].z = 1.0f - xv[j].z;  qv[j].w = 1.0f - xv[j].w;
    }

    float sgn[4];
    #pragma unroll
    for (int rr = 0; rr < 4; ++rr)
        sgn[rr] = (op[o_base + rr] == 0) ? -1.0f : 1.0f;   // min(v) = -max(-v)

    float acc[4];
    #pragma unroll
    for (int rr = 0; rr < 4; ++rr) acc[rr] = -3.0e38f;
    float accw = -3.0e38f;

    // SWEEP: 16 int4 loads (16 KB/wave in flight), then consume.
    // candidate: e==0 -> -2.0 (never wins; see R5 proof); e==2 -> s*(1-x); else s*x
#define SWEEP(P, ACCEXPR) { \
    iv4 e[16]; \
    _Pragma("unroll") \
    for (int rr = 0; rr < 4; ++rr) \
        _Pragma("unroll") \
        for (int j = 0; j < 4; ++j) e[rr * 4 + j] = (P)[rr * 256 + j * 64]; \
    _Pragma("unroll") \
    for (int rr = 0; rr < 4; ++rr) { \
        const float s = sgn[rr]; \
        _Pragma("unroll") \
        for (int j = 0; j < 4; ++j) { \
            const iv4 ev = e[rr * 4 + j]; \
            float c0, c1, c2, c3; \
            c0 = s * ((ev.x == 2) ? qv[j].x : xv[j].x);  c0 = (ev.x == 0) ? -2.0f : c0; \
            c1 = s * ((ev.y == 2) ? qv[j].y : xv[j].y);  c1 = (ev.y == 0) ? -2.0f : c1; \
            c2 = s * ((ev.z == 2) ? qv[j].z : xv[j].z);  c2 = (ev.z == 0) ? -2.0f : c2; \
            c3 = s * ((ev.w == 2) ? qv[j].w : xv[j].w);  c3 = (ev.w == 0) ? -2.0f : c3; \
            ACCEXPR = fmaxf(fmaxf(ACCEXPR, c0), c1); \
            ACCEXPR = fmaxf(fmaxf(ACCEXPR, c2), c3); \
        } \
    } }

    // Pass 0: the real et sweep (result goes to out)
    const iv4* pe = reinterpret_cast<const iv4*>(et + (size_t)r_base * I) + lane;
    SWEEP(pe, acc[rr])

    // Passes 1..nws: cold ws sweeps, identical pattern, dummy accumulator
    const iv4* pw = reinterpret_cast<const iv4*>(ws) + (size_t)wave * (ROWS_PER_WAVE * I / 4) + lane;
    for (int p = 0; p < 4; ++p) {
        if (p < nws) {
            const iv4* pp = pw + (size_t)p * REGION_IV4;
            SWEEP(pp, accw)
        }
    }
#undef SWEEP

    // real result
    float keep = 0.0f;
    #pragma unroll
    for (int rr = 0; rr < 4; ++rr) {
        float a = acc[rr];
        #pragma unroll
        for (int s = 32; s > 0; s >>= 1)
            a = fmaxf(a, __shfl_xor(a, s, 64));
        if (lane == rr) keep = sgn[rr] * a;
    }
    if (lane < ROWS_PER_WAVE)
        out[r_base + lane] = keep;

    // keep accw live; flag==0 at runtime -> never executes
    if (flag == 1 && lane == 63 && wave == 0)
        out[0] = accw;
}

extern "C" void kernel_launch(void* const* d_in, const int* in_sizes, int n_in,
                              void* d_out, int out_size, void* d_ws, size_t ws_size,
                              hipStream_t stream) {
    const float* x   = (const float*)d_in[0];
    const int*   et  = (const int*)d_in[1];
    const int*   op  = (const int*)d_in[2];
    float*       out = (float*)d_out;
    const int*   ws  = (const int*)d_ws;

    const size_t region_bytes = (size_t)B * O * I * 4;   // 268.4 MB
    int nws = (int)(ws_size / region_bytes);
    if (nws > 4) nws = 4;

    ffcl_probe<<<BLOCKS, 256, 0, stream>>>(x, et, op, out, ws, nws, 0L);
}

// Round 8
// 362.820 us; speedup vs baseline: 1.4987x; 1.4987x over previous
//
#include <hip/hip_runtime.h>

// ForwardForwardCountingLayer forward — persistent, steady-issue version.
//   per (b,o): out = sgn * max_i(candidate_i), sgn = is_tnorm ? -1 : +1
//   candidate = et==0 ? -2.0 : sgn * (et==2 ? 1-x : x)
// Sentinel proof: reference forces >=1 et!=0 per row; et!=0 candidates lie in
// (-1, 1]; true et==0 candidates after sgn-folding are <= -9; -2 sits strictly
// between, so it never wins and never needs the +/-10 offset math. Exact.
// s*(1-x) computed as s - s*x -> no 1-x table needed (16 x VGPRs, no LDS).
//
// Structure (R7 probe evidence): 1024 blocks x 4 waves = 16 waves/CU resident
// from t=0 (zero churn); each wave owns 16 consecutive rows (same b) and
// streams them through a 5-buffer rotating pipeline: ~16 KB/wave in flight
// continuously, vmcnt never drained to 0 until the tail.

constexpr int B = 64;
constexpr int I = 1024;
constexpr int O = 1024;
constexpr int ROWS_PER_WAVE  = 16;
constexpr int WAVES_PER_BLOCK = 4;
constexpr int BLOCKS = (B * O) / (ROWS_PER_WAVE * WAVES_PER_BLOCK);  // 1024

typedef int   iv4 __attribute__((ext_vector_type(4)));
typedef float fv4 __attribute__((ext_vector_type(4)));

__global__ __launch_bounds__(256, 4) void ffcl_kernel(
    const float* __restrict__ x,       // [B, I]
    const int*   __restrict__ et,      // [B, O, I]
    const int*   __restrict__ op,      // [O]
    float*       __restrict__ out)     // [B, O]
{
    const int t    = threadIdx.x;
    const int wid  = t >> 6;
    const int lane = t & 63;
    const int wave = blockIdx.x * WAVES_PER_BLOCK + wid;
    const int r0   = wave * ROWS_PER_WAVE;         // 16 consecutive rows, same b
    const int b    = r0 >> 10;
    const int o0   = r0 & (O - 1);

    // x strip for this lane: cols j*256 + lane*4 (16 floats, 16 VGPRs)
    fv4 xv[4];
    #pragma unroll
    for (int j = 0; j < 4; ++j)
        xv[j] = *reinterpret_cast<const fv4*>(x + (size_t)b * I + j * 256 + lane * 4);

    // per-row signs (wave-uniform -> SGPRs)
    float sgn[ROWS_PER_WAVE];
    #pragma unroll
    for (int rr = 0; rr < ROWS_PER_WAVE; ++rr)
        sgn[rr] = (op[o0 + rr] == 0) ? -1.0f : 1.0f;   // min(v) = -max(-v)

    const iv4* pe = reinterpret_cast<const iv4*>(et + (size_t)r0 * I) + lane;

    iv4 b0[4], b1[4], b2[4], b3[4], b4[4];   // 5 x 16 VGPR rotating buffers

#define LOADROW(BUF, RR) { _Pragma("unroll") \
    for (int j = 0; j < 4; ++j) BUF[j] = pe[(RR) * 256 + j * 64]; }

#define CONSUME(BUF, RR) { \
    const float s = sgn[RR]; \
    float a = -2.0f; \
    _Pragma("unroll") \
    for (int j = 0; j < 4; ++j) { \
        const iv4 ev = BUF[j]; \
        const float t0 = s * xv[j].x, t1 = s * xv[j].y, t2 = s * xv[j].z, t3 = s * xv[j].w; \
        float c0 = (ev.x == 2) ? s - t0 : t0;  c0 = (ev.x == 0) ? -2.0f : c0; \
        float c1 = (ev.y == 2) ? s - t1 : t1;  c1 = (ev.y == 0) ? -2.0f : c1; \
        float c2 = (ev.z == 2) ? s - t2 : t2;  c2 = (ev.z == 0) ? -2.0f : c2; \
        float c3 = (ev.w == 2) ? s - t3 : t3;  c3 = (ev.w == 0) ? -2.0f : c3; \
        a = fmaxf(fmaxf(a, c0), c1); \
        a = fmaxf(fmaxf(a, c2), c3); \
    } \
    _Pragma("unroll") \
    for (int sh = 32; sh > 0; sh >>= 1) a = fmaxf(a, __shfl_xor(a, sh, 64)); \
    if (lane == 0) out[r0 + (RR)] = s * a; }

    // prologue: fill the pipe 5 deep
    LOADROW(b0, 0) LOADROW(b1, 1) LOADROW(b2, 2) LOADROW(b3, 3) LOADROW(b4, 4)
    // steady state: consume row rr, immediately refill its buffer with rr+5
    CONSUME(b0, 0)   LOADROW(b0, 5)
    CONSUME(b1, 1)   LOADROW(b1, 6)
    CONSUME(b2, 2)   LOADROW(b2, 7)
    CONSUME(b3, 3)   LOADROW(b3, 8)
    CONSUME(b4, 4)   LOADROW(b4, 9)
    CONSUME(b0, 5)   LOADROW(b0, 10)
    CONSUME(b1, 6)   LOADROW(b1, 11)
    CONSUME(b2, 7)   LOADROW(b2, 12)
    CONSUME(b3, 8)   LOADROW(b3, 13)
    CONSUME(b4, 9)   LOADROW(b4, 14)
    CONSUME(b0, 10)  LOADROW(b0, 15)
    // drain
    CONSUME(b1, 11)
    CONSUME(b2, 12)
    CONSUME(b3, 13)
    CONSUME(b4, 14)
    CONSUME(b0, 15)
#undef LOADROW
#undef CONSUME
}

extern "C" void kernel_launch(void* const* d_in, const int* in_sizes, int n_in,
                              void* d_out, int out_size, void* d_ws, size_t ws_size,
                              hipStream_t stream) {
    const float* x   = (const float*)d_in[0];
    const int*   et  = (const int*)d_in[1];
    const int*   op  = (const int*)d_in[2];
    float*       out = (float*)d_out;

    ffcl_kernel<<<BLOCKS, 256, 0, stream>>>(x, et, op, out);
}